// Round 10
// baseline (4804.779 us; speedup 1.0000x reference)
//
#include <hip/hip_runtime.h>
#include <stdint.h>

namespace {

constexpr int B_   = 512;
constexpr int T_   = 512;
constexpr int IN_  = 6;
constexpr int H_   = 64;
constexpr int HH_  = 128;
constexpr int OUT_ = 8;

typedef _Float16 f16x2 __attribute__((ext_vector_type(2)));

__device__ __forceinline__ float dot2f(uint32_t w, uint32_t z, float acc) {
    return __builtin_amdgcn_fdot2(__builtin_bit_cast(f16x2, w),
                                  __builtin_bit_cast(f16x2, z), acc, false);
}

__device__ __forceinline__ uint32_t pack2f(float a, float b) {
    f16x2 p;
    p[0] = (_Float16)a;
    p[1] = (_Float16)b;
    return __builtin_bit_cast(uint32_t, p);
}

// sum across a 4-lane quad (kq = lane&3) via DPP quad_perm — pure VALU.
__device__ __forceinline__ float qsum4(float v) {
    int y = __builtin_amdgcn_mov_dpp(__builtin_bit_cast(int, v), 0xB1, 0xF, 0xF, true); // xor1
    v += __builtin_bit_cast(float, y);
    y = __builtin_amdgcn_mov_dpp(__builtin_bit_cast(int, v), 0x4E, 0xF, 0xF, true);     // xor2
    return v + __builtin_bit_cast(float, y);
}

__device__ __forceinline__ float tanh_fast(float v) {
    float ax = fabsf(v);
    float e  = __expf(2.0f * ax);
    float r  = 1.0f - 2.0f / (e + 1.0f);
    return copysignf(r, v);
}

// One workgroup (512 threads) per ONE batch element. Grid 512; VGPR ~112
// (<=128) lets the HW co-schedule 2 blocks/CU = 4 waves/SIMD at runtime.
// NOTE launch_bounds: on this toolchain, for 512-thread blocks arg2=N acts
// like N blocks/CU: (512,4) forced a 64-reg cap and spilled (R4/R9,
// WRITE_SIZE 100+ MB); (512,2) gives the 128-reg cap and R8 compiled this
// per-thread code shape to 112 regs with zero spill. Do not raise arg2.
// Thread t: col c = t>>2 (one z-column), k-quarter kq = t&3 -> weights
// 88 u32/thread, zero duplication. W_out cols {3c,3c+1,3c+2} -> A-row c>>1,
// dims (c&1)*3+{0,1,2}; row summed via __shfl_xor(4). RK4 state maintained
// in all lanes, written by (kq==0 && c even) lanes (64 writers = 64 h-rows).
__global__ __launch_bounds__(512, 2) void cde_kernel(
    const float* __restrict__ x,
    const float* __restrict__ W_init, const float* __restrict__ b_init,
    const float* __restrict__ W_in,   const float* __restrict__ b_in,
    const float* __restrict__ W_h1,   const float* __restrict__ b_h1,
    const float* __restrict__ W_h2,   const float* __restrict__ b_h2,
    const float* __restrict__ W_out,  const float* __restrict__ b_out,
    const float* __restrict__ W_fin,  const float* __restrict__ b_fin,
    float* __restrict__ out)
{
    const int t  = threadIdx.x;
    const int c  = t >> 2;      // 0..127 (z-column)
    const int kq = t & 3;       // k-quarter
    const int b  = blockIdx.x;

    __shared__ alignas(16) uint32_t hinu[H_ / 2];   // h as f16
    __shared__ alignas(16) uint32_t zAu[HH_ / 2];   // activation ping
    __shared__ alignas(16) uint32_t zBu[HH_ / 2];   // activation pong
    __shared__ float dxs[IN_];
    __shared__ float hbuf[H_];

    // ---- register-resident f16 weights: 8+16+16+48 = 88 u32, no duplication ----
    uint32_t w1[8], w2[16], w3[16], w4[48];
    #pragma unroll
    for (int i = 0; i < 8; ++i) {
        int k = kq * 16 + 2 * i;
        w1[i] = pack2f(W_in[k * HH_ + c], W_in[(k + 1) * HH_ + c]);
    }
    #pragma unroll
    for (int i = 0; i < 16; ++i) {
        int k = kq * 32 + 2 * i;
        w2[i] = pack2f(W_h1[k * HH_ + c], W_h1[(k + 1) * HH_ + c]);
        w3[i] = pack2f(W_h2[k * HH_ + c], W_h2[(k + 1) * HH_ + c]);
    }
    #pragma unroll
    for (int j = 0; j < 3; ++j) {
        const int col = 3 * c + j;
        #pragma unroll
        for (int i = 0; i < 16; ++i) {
            int k = kq * 32 + 2 * i;
            w4[j * 16 + i] = pack2f(W_out[k * 384 + col], W_out[(k + 1) * 384 + col]);
        }
    }
    const float bin_r = b_in[c];
    const float bh1_r = b_h1[c];
    const float bh2_r = b_h2[c];
    float bo[3];
    #pragma unroll
    for (int j = 0; j < 3; ++j) bo[j] = b_out[3 * c + j];
    const int  dbase = (c & 1) * 3;   // dim offset of this thread's 3 A-cols
    const int  r_own = c >> 1;        // h-row this thread's pair reduces
    const bool wrt   = (kq == 0) && ((c & 1) == 0);   // state writer lanes
    const float bfin_r = (t < 64) ? b_fin[t & 7] : 0.0f;

    float wfr[8];
    #pragma unroll
    for (int j = 0; j < 8; ++j)
        wfr[j] = (t < 64) ? W_fin[((t >> 3) * 8 + j) * OUT_ + (t & 7)] : 0.0f;

    const size_t xbase = (size_t)b * T_ * IN_;
    const size_t obase = (size_t)b * T_ * OUT_;

    // dX producer: threads 0..5
    float xa = 0.f, xb = 0.f;
    if (t < IN_) {
        xa = x[xbase + t];
        xb = x[xbase + IN_ + t];
        dxs[t] = xb - xa;                 // dX for step 0
        xa = xb;
        xb = x[xbase + 2 * IN_ + t];
    }

    // ---- h0 (threads t<64) ----
    if (t < H_) {
        float s = b_init[t];
        #pragma unroll
        for (int i = 0; i < IN_; ++i) s += x[xbase + i] * W_init[i * H_ + t];
        hbuf[t] = s;
        ((_Float16*)hinu)[t] = (_Float16)s;
    }
    __syncthreads();

    // RK4 state (maintained redundantly in all lanes of the row pair)
    float h_reg = hbuf[r_own];
    float hacc  = 0.f;

#define OUT_STAGE(TT)                                                          \
    if (t < 64) {                                                              \
        int o_ = t & 7, part_ = t >> 3;                                        \
        float s_ = 0.f;                                                        \
        _Pragma("unroll")                                                      \
        for (int j = 0; j < 8; ++j) s_ += hbuf[part_ * 8 + j] * wfr[j];        \
        s_ += __shfl_xor(s_, 8);                                               \
        s_ += __shfl_xor(s_, 16);                                              \
        s_ += __shfl_xor(s_, 32);                                              \
        if (part_ == 0)                                                        \
            out[obase + (size_t)(TT) * OUT_ + o_] = s_ + bfin_r;               \
    }

    OUT_STAGE(0)

    float dxr[3];

    for (int step = 0; step < T_ - 1; ++step) {
        #pragma unroll
        for (int s4 = 0; s4 < 4; ++s4) {
            // ---- phase 1: (dx reload + out-stage on s4==0) + G1: h -> z1 ----
            if (s4 == 0) {
                #pragma unroll
                for (int j = 0; j < 3; ++j) dxr[j] = dxs[dbase + j];
                if (step > 0) { OUT_STAGE(step) }
            }
            {
                const uint32_t* hp = hinu + kq * 8;
                uint4 q0 = *reinterpret_cast<const uint4*>(hp);
                uint4 q1 = *reinterpret_cast<const uint4*>(hp + 4);
                float a = 0.f, d = 0.f;
                a = dot2f(w1[0], q0.x, a); d = dot2f(w1[1], q0.y, d);
                a = dot2f(w1[2], q0.z, a); d = dot2f(w1[3], q0.w, d);
                a = dot2f(w1[4], q1.x, a); d = dot2f(w1[5], q1.y, d);
                a = dot2f(w1[6], q1.z, a); d = dot2f(w1[7], q1.w, d);
                float z = fmaxf(bin_r + qsum4(a + d), 0.f);
                if (kq == 0) ((_Float16*)zAu)[c] = (_Float16)z;
            }
            __syncthreads();

            // ---- phase 2: G2 zA -> zB ----
            {
                const uint32_t* zp = zAu + kq * 16;
                uint4 q0 = *reinterpret_cast<const uint4*>(zp);
                uint4 q1 = *reinterpret_cast<const uint4*>(zp + 4);
                uint4 q2 = *reinterpret_cast<const uint4*>(zp + 8);
                uint4 q3 = *reinterpret_cast<const uint4*>(zp + 12);
                float a = 0.f, d = 0.f;
                #pragma unroll
                for (int m = 0; m < 4; ++m) {
                    a = dot2f(w2[m],      (&q0.x)[m], a);
                    d = dot2f(w2[4 + m],  (&q1.x)[m], d);
                    a = dot2f(w2[8 + m],  (&q2.x)[m], a);
                    d = dot2f(w2[12 + m], (&q3.x)[m], d);
                }
                float z = fmaxf(bh1_r + qsum4(a + d), 0.f);
                if (kq == 0) ((_Float16*)zBu)[c] = (_Float16)z;
            }
            __syncthreads();

            // ---- phase 3: G3 zB -> zA ----
            {
                const uint32_t* zp = zBu + kq * 16;
                uint4 q0 = *reinterpret_cast<const uint4*>(zp);
                uint4 q1 = *reinterpret_cast<const uint4*>(zp + 4);
                uint4 q2 = *reinterpret_cast<const uint4*>(zp + 8);
                uint4 q3 = *reinterpret_cast<const uint4*>(zp + 12);
                float a = 0.f, d = 0.f;
                #pragma unroll
                for (int m = 0; m < 4; ++m) {
                    a = dot2f(w3[m],      (&q0.x)[m], a);
                    d = dot2f(w3[4 + m],  (&q1.x)[m], d);
                    a = dot2f(w3[8 + m],  (&q2.x)[m], a);
                    d = dot2f(w3[12 + m], (&q3.x)[m], d);
                }
                float z = fmaxf(bh2_r + qsum4(a + d), 0.f);
                if (kq == 0) ((_Float16*)zAu)[c] = (_Float16)z;
            }
            __syncthreads();

            // ---- phase 4: G4 (3 A-cols) + pair-sum einsum + RK4 ----
            {
                const uint32_t* zp = zAu + kq * 16;
                uint4 q0 = *reinterpret_cast<const uint4*>(zp);
                uint4 q1 = *reinterpret_cast<const uint4*>(zp + 4);
                uint4 q2 = *reinterpret_cast<const uint4*>(zp + 8);
                uint4 q3 = *reinterpret_cast<const uint4*>(zp + 12);
                float av0 = 0.f, av1 = 0.f, av2 = 0.f;
                #pragma unroll
                for (int m = 0; m < 4; ++m) {
                    uint32_t z0 = (&q0.x)[m], z1 = (&q1.x)[m], z2 = (&q2.x)[m], z3 = (&q3.x)[m];
                    av0 = dot2f(w4[m],      z0, av0); av0 = dot2f(w4[4 + m],  z1, av0);
                    av0 = dot2f(w4[8 + m],  z2, av0); av0 = dot2f(w4[12 + m], z3, av0);
                    av1 = dot2f(w4[16 + m], z0, av1); av1 = dot2f(w4[20 + m], z1, av1);
                    av1 = dot2f(w4[24 + m], z2, av1); av1 = dot2f(w4[28 + m], z3, av1);
                    av2 = dot2f(w4[32 + m], z0, av2); av2 = dot2f(w4[36 + m], z1, av2);
                    av2 = dot2f(w4[40 + m], z2, av2); av2 = dot2f(w4[44 + m], z3, av2);
                }
                av0 = qsum4(av0); av1 = qsum4(av1); av2 = qsum4(av2);
                float kvp = tanh_fast(bo[0] + av0) * dxr[0]
                          + tanh_fast(bo[1] + av1) * dxr[1]
                          + tanh_fast(bo[2] + av2) * dxr[2];
                float kv = kvp + __shfl_xor(kvp, 4);   // pair (c, c^1) -> full row sum

                hacc += ((s4 == 1 || s4 == 2) ? 2.0f : 1.0f) * kv;
                float hs;
                if (s4 < 3) {
                    hs = h_reg + ((s4 == 2) ? 1.0f : 0.5f) * kv;
                } else {
                    h_reg += hacc * (1.0f / 6.0f);
                    hacc = 0.f;
                    hs = h_reg;
                }
                if (wrt) {
                    ((_Float16*)hinu)[r_own] = (_Float16)hs;
                    if (s4 == 3) hbuf[r_own] = h_reg;
                }
            }
            // dX for step+1 (read at next step's s4==0, after the barrier below)
            if (s4 == 3 && step + 2 < T_ && t < IN_) {
                dxs[t] = xb - xa;
                xa = xb;
                if (step + 3 < T_) xb = x[xbase + (size_t)(step + 3) * IN_ + t];
            }
            __syncthreads();
        }
    }

    OUT_STAGE(T_ - 1)
#undef OUT_STAGE
}

} // namespace

extern "C" void kernel_launch(void* const* d_in, const int* in_sizes, int n_in,
                              void* d_out, int out_size, void* d_ws, size_t ws_size,
                              hipStream_t stream) {
    const float* x      = (const float*)d_in[0];
    const float* W_init = (const float*)d_in[1];
    const float* b_init = (const float*)d_in[2];
    const float* W_in   = (const float*)d_in[3];
    const float* b_in   = (const float*)d_in[4];
    const float* W_h1   = (const float*)d_in[5];
    const float* b_h1   = (const float*)d_in[6];
    const float* W_h2   = (const float*)d_in[7];
    const float* b_h2   = (const float*)d_in[8];
    const float* W_out  = (const float*)d_in[9];
    const float* b_out  = (const float*)d_in[10];
    const float* W_fin  = (const float*)d_in[11];
    const float* b_fin  = (const float*)d_in[12];
    float* out = (float*)d_out;

    cde_kernel<<<dim3(B_), dim3(512), 0, stream>>>(
        x, W_init, b_init, W_in, b_in, W_h1, b_h1, W_h2, b_h2,
        W_out, b_out, W_fin, b_fin, out);
}

// Round 11
// 3228.750 us; speedup vs baseline: 1.4881x; 1.4881x over previous
//
#include <hip/hip_runtime.h>
#include <stdint.h>

namespace {

constexpr int B_   = 512;
constexpr int T_   = 512;
constexpr int IN_  = 6;
constexpr int H_   = 64;
constexpr int HH_  = 128;
constexpr int OUT_ = 8;

typedef _Float16 f16x2 __attribute__((ext_vector_type(2)));

__device__ __forceinline__ float dot2f(uint32_t w, uint32_t z, float acc) {
    return __builtin_amdgcn_fdot2(__builtin_bit_cast(f16x2, w),
                                  __builtin_bit_cast(f16x2, z), acc, false);
}

__device__ __forceinline__ uint32_t pack2f(float a, float b) {
    f16x2 p;
    p[0] = (_Float16)a;
    p[1] = (_Float16)b;
    return __builtin_bit_cast(uint32_t, p);
}

// pair sum across kh lanes (t ^ 1) via DPP quad_perm [1,0,3,2] — pure VALU.
__device__ __forceinline__ float pxor1(float v) {
    int y = __builtin_amdgcn_mov_dpp(__builtin_bit_cast(int, v), 0xB1, 0xF, 0xF, true);
    return v + __builtin_bit_cast(float, y);
}

// pair sum across c-parity lanes (t ^ 2) via DPP quad_perm [2,3,0,1].
__device__ __forceinline__ float pxor2(float v) {
    int y = __builtin_amdgcn_mov_dpp(__builtin_bit_cast(int, v), 0x4E, 0xF, 0xF, true);
    return v + __builtin_bit_cast(float, y);
}

__device__ __forceinline__ float tanh_fast(float v) {
    float ax = fabsf(v);
    float e  = __expf(2.0f * ax);
    float r  = 1.0f - 2.0f / (e + 1.0f);
    return copysignf(r, v);
}

// One workgroup (256 threads) per ONE batch element, grid 512.
// Empirical occupancy rule (R3..R10): effective reg cost ~ 2x VGPR_Count;
// at VGPR<=128 two 256-thr blocks co-reside per CU (8 waves) with
// INDEPENDENT barriers that interleave — the R3 configuration (best: 3605us).
// This version removes R3's taxes: in-register einsum (4 barriers/eval, no
// pp[] round-trip), all-lane RK4, W_in in LDS ([kp][c] layout: 2-way
// broadcast reads, conflict-free), W_fin/b_fin in LDS.
// Thread t: z-col c = t>>1, k-half kh = t&1. Weights in regs: w2,w3 (32 ea),
// w4 (96) = 160 u32. W_out cols {3c,3c+1,3c+2} -> A-row c>>1 (= t>>2),
// dims (c&1)*3+{0,1,2}; kh-reduce via pxor1, row-reduce via pxor2.
__global__ __launch_bounds__(256, 2) void cde_kernel(
    const float* __restrict__ x,
    const float* __restrict__ W_init, const float* __restrict__ b_init,
    const float* __restrict__ W_in,   const float* __restrict__ b_in,
    const float* __restrict__ W_h1,   const float* __restrict__ b_h1,
    const float* __restrict__ W_h2,   const float* __restrict__ b_h2,
    const float* __restrict__ W_out,  const float* __restrict__ b_out,
    const float* __restrict__ W_fin,  const float* __restrict__ b_fin,
    float* __restrict__ out)
{
    const int t  = threadIdx.x;
    const int c  = t >> 1;      // 0..127 (z-column)
    const int kh = t & 1;       // k-half
    const int b  = blockIdx.x;

    __shared__ alignas(16) uint32_t hinu[H_ / 2];    // h as f16 pairs
    __shared__ alignas(16) uint32_t zAu[HH_ / 2];    // activation ping
    __shared__ alignas(16) uint32_t zBu[HH_ / 2];    // activation pong
    __shared__ uint32_t w1s[32 * HH_];               // W_in packed [kp][c], 16KB
    __shared__ float dxs[IN_];
    __shared__ float hbuf[H_];
    __shared__ float wfin_s[H_ * OUT_];
    __shared__ float bfin_s[OUT_];

    // ---- register-resident f16 weights (k-half slice): 32+32+96 = 160 u32 ----
    uint32_t w2[32], w3[32], w4[96];
    #pragma unroll
    for (int i = 0; i < 32; ++i) {
        int k = kh * 64 + 2 * i;
        w2[i] = pack2f(W_h1[k * HH_ + c], W_h1[(k + 1) * HH_ + c]);
        w3[i] = pack2f(W_h2[k * HH_ + c], W_h2[(k + 1) * HH_ + c]);
    }
    #pragma unroll
    for (int j = 0; j < 3; ++j) {
        const int col = 3 * c + j;
        #pragma unroll
        for (int i = 0; i < 32; ++i) {
            int k = kh * 64 + 2 * i;
            w4[j * 32 + i] = pack2f(W_out[k * 384 + col], W_out[(k + 1) * 384 + col]);
        }
    }
    // W_in -> LDS, packed k-pairs, layout [kp][c] (reads: 2-lane broadcast, 0-conflict)
    for (int i = t; i < 32 * HH_; i += 256) {
        int kp = i >> 7, cc = i & 127;
        w1s[i] = pack2f(W_in[(2 * kp) * HH_ + cc], W_in[(2 * kp + 1) * HH_ + cc]);
    }
    for (int i = t; i < H_ * OUT_; i += 256) wfin_s[i] = W_fin[i];
    if (t < OUT_) bfin_s[t] = b_fin[t];

    const float bin_r = b_in[c];
    const float bh1_r = b_h1[c];
    const float bh2_r = b_h2[c];
    float bo[3];
    #pragma unroll
    for (int j = 0; j < 3; ++j) bo[j] = b_out[3 * c + j];
    const int  dbase = (c & 1) * 3;   // dX dims of this thread's 3 A-cols
    const int  r_own = t >> 2;        // A/h row this quad owns
    const bool wrt   = (t & 3) == 0;  // state writer lanes (64 = 64 rows)

    const size_t xbase = (size_t)b * T_ * IN_;
    const size_t obase = (size_t)b * T_ * OUT_;

    // dX producer: threads 0..5
    float xa = 0.f, xb = 0.f;
    if (t < IN_) {
        xa = x[xbase + t];
        xb = x[xbase + IN_ + t];
        dxs[t] = xb - xa;                 // dX for step 0
        xa = xb;
        xb = x[xbase + 2 * IN_ + t];
    }

    // ---- h0 (threads t<64) ----
    if (t < H_) {
        float s = b_init[t];
        #pragma unroll
        for (int i = 0; i < IN_; ++i) s += x[xbase + i] * W_init[i * H_ + t];
        hbuf[t] = s;
        ((_Float16*)hinu)[t] = (_Float16)s;
    }
    __syncthreads();

    // RK4 state (maintained redundantly in the 4 lanes of each row quad)
    float h_reg = hbuf[r_own];
    float hacc  = 0.f;

#define OUT_STAGE(TT)                                                          \
    if (t < 64) {                                                              \
        int o_ = t & 7, part_ = t >> 3;                                        \
        float s_ = 0.f;                                                        \
        _Pragma("unroll")                                                      \
        for (int j = 0; j < 8; ++j)                                            \
            s_ += hbuf[part_ * 8 + j] * wfin_s[(part_ * 8 + j) * OUT_ + o_];   \
        s_ += __shfl_xor(s_, 8);                                               \
        s_ += __shfl_xor(s_, 16);                                              \
        s_ += __shfl_xor(s_, 32);                                              \
        if (part_ == 0)                                                        \
            out[obase + (size_t)(TT) * OUT_ + o_] = s_ + bfin_s[o_];           \
    }

    OUT_STAGE(0)

    float dxr[3];

    for (int step = 0; step < T_ - 1; ++step) {
        #pragma unroll
        for (int s4 = 0; s4 < 4; ++s4) {
            // ---- phase 1: (dxr reload + out-stage on s4==0) + G1: h -> z1 ----
            if (s4 == 0) {
                #pragma unroll
                for (int j = 0; j < 3; ++j) dxr[j] = dxs[dbase + j];
                if (step > 0) { OUT_STAGE(step) }
            }
            {
                uint32_t hv[16];
                const uint32_t* hp = hinu + kh * 16;
                *(uint4*)&hv[0]  = *(const uint4*)(hp);
                *(uint4*)&hv[4]  = *(const uint4*)(hp + 4);
                *(uint4*)&hv[8]  = *(const uint4*)(hp + 8);
                *(uint4*)&hv[12] = *(const uint4*)(hp + 12);
                const int w1base = (kh * 16) * HH_ + c;
                float a0 = 0.f, a1 = 0.f, a2 = 0.f, a3 = 0.f;
                #pragma unroll
                for (int i = 0; i < 16; ++i) {
                    uint32_t wv = w1s[w1base + i * HH_];
                    if ((i & 3) == 0)      a0 = dot2f(wv, hv[i], a0);
                    else if ((i & 3) == 1) a1 = dot2f(wv, hv[i], a1);
                    else if ((i & 3) == 2) a2 = dot2f(wv, hv[i], a2);
                    else                   a3 = dot2f(wv, hv[i], a3);
                }
                float z = fmaxf(bin_r + pxor1((a0 + a1) + (a2 + a3)), 0.f);
                if (kh == 0) ((_Float16*)zAu)[c] = (_Float16)z;
            }
            __syncthreads();

            // ---- phase 2: G2 zA -> zB ----
            {
                uint32_t zv[32];
                const uint32_t* zp = zAu + kh * 32;
                #pragma unroll
                for (int q = 0; q < 8; ++q)
                    *(uint4*)&zv[4 * q] = *(const uint4*)(zp + 4 * q);
                float a0 = 0.f, a1 = 0.f, a2 = 0.f, a3 = 0.f;
                #pragma unroll
                for (int i = 0; i < 32; ++i) {
                    if ((i & 3) == 0)      a0 = dot2f(w2[i], zv[i], a0);
                    else if ((i & 3) == 1) a1 = dot2f(w2[i], zv[i], a1);
                    else if ((i & 3) == 2) a2 = dot2f(w2[i], zv[i], a2);
                    else                   a3 = dot2f(w2[i], zv[i], a3);
                }
                float z = fmaxf(bh1_r + pxor1((a0 + a1) + (a2 + a3)), 0.f);
                if (kh == 0) ((_Float16*)zBu)[c] = (_Float16)z;
            }
            __syncthreads();

            // ---- phase 3: G3 zB -> zA ----
            {
                uint32_t zv[32];
                const uint32_t* zp = zBu + kh * 32;
                #pragma unroll
                for (int q = 0; q < 8; ++q)
                    *(uint4*)&zv[4 * q] = *(const uint4*)(zp + 4 * q);
                float a0 = 0.f, a1 = 0.f, a2 = 0.f, a3 = 0.f;
                #pragma unroll
                for (int i = 0; i < 32; ++i) {
                    if ((i & 3) == 0)      a0 = dot2f(w3[i], zv[i], a0);
                    else if ((i & 3) == 1) a1 = dot2f(w3[i], zv[i], a1);
                    else if ((i & 3) == 2) a2 = dot2f(w3[i], zv[i], a2);
                    else                   a3 = dot2f(w3[i], zv[i], a3);
                }
                float z = fmaxf(bh2_r + pxor1((a0 + a1) + (a2 + a3)), 0.f);
                if (kh == 0) ((_Float16*)zAu)[c] = (_Float16)z;
            }
            __syncthreads();

            // ---- phase 4: G4 (3 A-cols) + in-register einsum + RK4 ----
            {
                uint32_t zv[32];
                const uint32_t* zp = zAu + kh * 32;
                #pragma unroll
                for (int q = 0; q < 8; ++q)
                    *(uint4*)&zv[4 * q] = *(const uint4*)(zp + 4 * q);
                float p0 = 0.f, p1 = 0.f, p2 = 0.f, p3 = 0.f, p4 = 0.f, p5 = 0.f;
                #pragma unroll
                for (int i = 0; i < 16; ++i) {
                    uint32_t ze = zv[2 * i], zo = zv[2 * i + 1];
                    p0 = dot2f(w4[2 * i],          ze, p0);
                    p1 = dot2f(w4[2 * i + 1],      zo, p1);
                    p2 = dot2f(w4[32 + 2 * i],     ze, p2);
                    p3 = dot2f(w4[32 + 2 * i + 1], zo, p3);
                    p4 = dot2f(w4[64 + 2 * i],     ze, p4);
                    p5 = dot2f(w4[64 + 2 * i + 1], zo, p5);
                }
                float av0 = bo[0] + pxor1(p0 + p1);
                float av1 = bo[1] + pxor1(p2 + p3);
                float av2 = bo[2] + pxor1(p4 + p5);
                float kvp = tanh_fast(av0) * dxr[0]
                          + tanh_fast(av1) * dxr[1]
                          + tanh_fast(av2) * dxr[2];
                float kv = pxor2(kvp);          // row-pair (c, c^1) -> full row sum

                hacc += ((s4 == 1 || s4 == 2) ? 2.0f : 1.0f) * kv;
                float hs;
                if (s4 < 3) {
                    hs = h_reg + ((s4 == 2) ? 1.0f : 0.5f) * kv;
                } else {
                    h_reg += hacc * (1.0f / 6.0f);
                    hacc = 0.f;
                    hs = h_reg;
                }
                if (wrt) {
                    ((_Float16*)hinu)[r_own] = (_Float16)hs;
                    if (s4 == 3) hbuf[r_own] = h_reg;
                }
            }
            // dX for step+1 (read at next step's s4==0, after the barrier below)
            if (s4 == 3 && step + 2 < T_ && t < IN_) {
                dxs[t] = xb - xa;
                xa = xb;
                if (step + 3 < T_) xb = x[xbase + (size_t)(step + 3) * IN_ + t];
            }
            __syncthreads();
        }
    }

    OUT_STAGE(T_ - 1)
#undef OUT_STAGE
}

} // namespace

extern "C" void kernel_launch(void* const* d_in, const int* in_sizes, int n_in,
                              void* d_out, int out_size, void* d_ws, size_t ws_size,
                              hipStream_t stream) {
    const float* x      = (const float*)d_in[0];
    const float* W_init = (const float*)d_in[1];
    const float* b_init = (const float*)d_in[2];
    const float* W_in   = (const float*)d_in[3];
    const float* b_in   = (const float*)d_in[4];
    const float* W_h1   = (const float*)d_in[5];
    const float* b_h1   = (const float*)d_in[6];
    const float* W_h2   = (const float*)d_in[7];
    const float* b_h2   = (const float*)d_in[8];
    const float* W_out  = (const float*)d_in[9];
    const float* b_out  = (const float*)d_in[10];
    const float* W_fin  = (const float*)d_in[11];
    const float* b_fin  = (const float*)d_in[12];
    float* out = (float*)d_out;

    cde_kernel<<<dim3(B_), dim3(256), 0, stream>>>(
        x, W_init, b_init, W_in, b_in, W_h1, b_h1, W_h2, b_h2,
        W_out, b_out, W_fin, b_fin, out);
}